// Round 7
// baseline (89.997 us; speedup 1.0000x reference)
//
#include <hip/hip_runtime.h>
#include <cmath>

// Single fused kernel: coalesced LDS staging + b128 LDS GEMV, R=2 rows/thread.
//
// Math: angles = tanh(x@W^T + b); fixed 3-layer circuit = constant 16x16
// unitary U; output collapses to an 81x4 tensor A contracted with g[9]xh[9]
// built from sincos(angles). A recomputed per block in LDS (~2-3us, all
// blocks concurrent).
//
// Staging: per 16-feature chunk, each thread loads one float4 such that 4
// adjacent lanes fully consume one 64B line in one instruction (exact-once
// HBM fetch), writes b128 into xt with word-stride 20 (16B-aligned rows,
// bank-balanced: 8 requests/bank = peak throughput), then reads its own
// row back as 4x ds_read_b128. rbA/rbB ping-pong keeps next chunk's loads
// in flight under the current GEMV. All angle/contraction work happens
// after the final barrier (no arrays live across barriers -> no scratch).

#define LOADX(RB, P, C)                                   \
  RB[0] = xb[((P) * 256 + 0 * 64) * 16 + (C) * 4];        \
  RB[1] = xb[((P) * 256 + 1 * 64) * 16 + (C) * 4];        \
  RB[2] = xb[((P) * 256 + 2 * 64) * 16 + (C) * 4];        \
  RB[3] = xb[((P) * 256 + 3 * 64) * 16 + (C) * 4];

#define STAGE(RB)                                                          \
  *reinterpret_cast<float4*>(&lds[(0 * 64 + rrow) * XS + q4w]) = RB[0];    \
  *reinterpret_cast<float4*>(&lds[(1 * 64 + rrow) * XS + q4w]) = RB[1];    \
  *reinterpret_cast<float4*>(&lds[(2 * 64 + rrow) * XS + q4w]) = RB[2];    \
  *reinterpret_cast<float4*>(&lds[(3 * 64 + rrow) * XS + q4w]) = RB[3];

#define GEMV(A0, A1, A2, A3, C) {                                          \
  const float4 xv0 = *reinterpret_cast<const float4*>(&lds[tid * XS + 0]); \
  const float4 xv1 = *reinterpret_cast<const float4*>(&lds[tid * XS + 4]); \
  const float4 xv2 = *reinterpret_cast<const float4*>(&lds[tid * XS + 8]); \
  const float4 xv3 = *reinterpret_cast<const float4*>(&lds[tid * XS + 12]);\
  A0 = fmaf(xv0.x, Wp[0 * 64 + (C) * 16 + 0], A0);                         \
  A0 = fmaf(xv0.y, Wp[0 * 64 + (C) * 16 + 1], A0);                         \
  A0 = fmaf(xv0.z, Wp[0 * 64 + (C) * 16 + 2], A0);                         \
  A0 = fmaf(xv0.w, Wp[0 * 64 + (C) * 16 + 3], A0);                         \
  A0 = fmaf(xv1.x, Wp[0 * 64 + (C) * 16 + 4], A0);                         \
  A0 = fmaf(xv1.y, Wp[0 * 64 + (C) * 16 + 5], A0);                         \
  A0 = fmaf(xv1.z, Wp[0 * 64 + (C) * 16 + 6], A0);                         \
  A0 = fmaf(xv1.w, Wp[0 * 64 + (C) * 16 + 7], A0);                         \
  A0 = fmaf(xv2.x, Wp[0 * 64 + (C) * 16 + 8], A0);                         \
  A0 = fmaf(xv2.y, Wp[0 * 64 + (C) * 16 + 9], A0);                         \
  A0 = fmaf(xv2.z, Wp[0 * 64 + (C) * 16 + 10], A0);                        \
  A0 = fmaf(xv2.w, Wp[0 * 64 + (C) * 16 + 11], A0);                        \
  A0 = fmaf(xv3.x, Wp[0 * 64 + (C) * 16 + 12], A0);                        \
  A0 = fmaf(xv3.y, Wp[0 * 64 + (C) * 16 + 13], A0);                        \
  A0 = fmaf(xv3.z, Wp[0 * 64 + (C) * 16 + 14], A0);                        \
  A0 = fmaf(xv3.w, Wp[0 * 64 + (C) * 16 + 15], A0);                        \
  A1 = fmaf(xv0.x, Wp[1 * 64 + (C) * 16 + 0], A1);                         \
  A1 = fmaf(xv0.y, Wp[1 * 64 + (C) * 16 + 1], A1);                         \
  A1 = fmaf(xv0.z, Wp[1 * 64 + (C) * 16 + 2], A1);                         \
  A1 = fmaf(xv0.w, Wp[1 * 64 + (C) * 16 + 3], A1);                         \
  A1 = fmaf(xv1.x, Wp[1 * 64 + (C) * 16 + 4], A1);                         \
  A1 = fmaf(xv1.y, Wp[1 * 64 + (C) * 16 + 5], A1);                         \
  A1 = fmaf(xv1.z, Wp[1 * 64 + (C) * 16 + 6], A1);                         \
  A1 = fmaf(xv1.w, Wp[1 * 64 + (C) * 16 + 7], A1);                         \
  A1 = fmaf(xv2.x, Wp[1 * 64 + (C) * 16 + 8], A1);                         \
  A1 = fmaf(xv2.y, Wp[1 * 64 + (C) * 16 + 9], A1);                         \
  A1 = fmaf(xv2.z, Wp[1 * 64 + (C) * 16 + 10], A1);                        \
  A1 = fmaf(xv2.w, Wp[1 * 64 + (C) * 16 + 11], A1);                        \
  A1 = fmaf(xv3.x, Wp[1 * 64 + (C) * 16 + 12], A1);                        \
  A1 = fmaf(xv3.y, Wp[1 * 64 + (C) * 16 + 13], A1);                        \
  A1 = fmaf(xv3.z, Wp[1 * 64 + (C) * 16 + 14], A1);                        \
  A1 = fmaf(xv3.w, Wp[1 * 64 + (C) * 16 + 15], A1);                        \
  A2 = fmaf(xv0.x, Wp[2 * 64 + (C) * 16 + 0], A2);                         \
  A2 = fmaf(xv0.y, Wp[2 * 64 + (C) * 16 + 1], A2);                         \
  A2 = fmaf(xv0.z, Wp[2 * 64 + (C) * 16 + 2], A2);                         \
  A2 = fmaf(xv0.w, Wp[2 * 64 + (C) * 16 + 3], A2);                         \
  A2 = fmaf(xv1.x, Wp[2 * 64 + (C) * 16 + 4], A2);                         \
  A2 = fmaf(xv1.y, Wp[2 * 64 + (C) * 16 + 5], A2);                         \
  A2 = fmaf(xv1.z, Wp[2 * 64 + (C) * 16 + 6], A2);                         \
  A2 = fmaf(xv1.w, Wp[2 * 64 + (C) * 16 + 7], A2);                         \
  A2 = fmaf(xv2.x, Wp[2 * 64 + (C) * 16 + 8], A2);                         \
  A2 = fmaf(xv2.y, Wp[2 * 64 + (C) * 16 + 9], A2);                         \
  A2 = fmaf(xv2.z, Wp[2 * 64 + (C) * 16 + 10], A2);                        \
  A2 = fmaf(xv2.w, Wp[2 * 64 + (C) * 16 + 11], A2);                        \
  A2 = fmaf(xv3.x, Wp[2 * 64 + (C) * 16 + 12], A2);                        \
  A2 = fmaf(xv3.y, Wp[2 * 64 + (C) * 16 + 13], A2);                        \
  A2 = fmaf(xv3.z, Wp[2 * 64 + (C) * 16 + 14], A2);                        \
  A2 = fmaf(xv3.w, Wp[2 * 64 + (C) * 16 + 15], A2);                        \
  A3 = fmaf(xv0.x, Wp[3 * 64 + (C) * 16 + 0], A3);                         \
  A3 = fmaf(xv0.y, Wp[3 * 64 + (C) * 16 + 1], A3);                         \
  A3 = fmaf(xv0.z, Wp[3 * 64 + (C) * 16 + 2], A3);                         \
  A3 = fmaf(xv0.w, Wp[3 * 64 + (C) * 16 + 3], A3);                         \
  A3 = fmaf(xv1.x, Wp[3 * 64 + (C) * 16 + 4], A3);                         \
  A3 = fmaf(xv1.y, Wp[3 * 64 + (C) * 16 + 5], A3);                         \
  A3 = fmaf(xv1.z, Wp[3 * 64 + (C) * 16 + 6], A3);                         \
  A3 = fmaf(xv1.w, Wp[3 * 64 + (C) * 16 + 7], A3);                         \
  A3 = fmaf(xv2.x, Wp[3 * 64 + (C) * 16 + 8], A3);                         \
  A3 = fmaf(xv2.y, Wp[3 * 64 + (C) * 16 + 9], A3);                         \
  A3 = fmaf(xv2.z, Wp[3 * 64 + (C) * 16 + 10], A3);                        \
  A3 = fmaf(xv2.w, Wp[3 * 64 + (C) * 16 + 11], A3);                        \
  A3 = fmaf(xv3.x, Wp[3 * 64 + (C) * 16 + 12], A3);                        \
  A3 = fmaf(xv3.y, Wp[3 * 64 + (C) * 16 + 13], A3);                        \
  A3 = fmaf(xv3.z, Wp[3 * 64 + (C) * 16 + 14], A3);                        \
  A3 = fmaf(xv3.w, Wp[3 * 64 + (C) * 16 + 15], A3); }

__global__ __launch_bounds__(256, 4) void qfused_kernel(
    const float* __restrict__ x,    // [B][64]
    const float* __restrict__ Wp,   // [4][64]
    const float* __restrict__ bp,   // [4]
    const float* __restrict__ qw,   // [3][4][2]
    float* __restrict__ out)        // [B][4]
{
  constexpr int XS  = 20;           // xt word stride: 80B rows, 16B-aligned
  constexpr int AOF = 256 * XS;     // 5120
  __shared__ alignas(16) float lds[256 * XS + 324];   // 21.3 KB
  constexpr int SRE = 0;            // prep scratch inside xt region (dead later)
  constexpr int SIM = 272;
  constexpr int MOF = 544;

  const int tid = threadIdx.x;
  const size_t row0 = (size_t)blockIdx.x * 512;
  const int rrow = tid >> 2;            // staging row within 64-row group
  const int q4w  = (tid & 3) << 2;      // word offset within 16-feat chunk
  // lane's base: float4 #(tid&3) of chunk 0 of row (row0 + rrow)
  const float4* xb = reinterpret_cast<const float4*>(x) +
                     (row0 + (size_t)rrow) * 16 + (tid & 3);

  // ---- prefetch (phase0, chunk0); in flight during prep ----
  float4 rbA[4], rbB[4];
  LOADX(rbA, 0, 0);

  // ---- prep: build A[81][4] at lds[AOF] (256 thr = 16 cols x 16 amps) ----
  {
    const int col = tid >> 4;
    const int u   = tid & 15;
    lds[SRE + col * 17 + u] = (u == col) ? 1.0f : 0.0f;
    lds[SIM + col * 17 + u] = 0.0f;
    __syncthreads();

#pragma unroll
    for (int l = 0; l < 3; ++l) {
#pragma unroll
      for (int w = 0; w < 4; ++w) {
        const int mask = 8 >> w;     // wire 0 = MSB
        float sh, ch, sh2, ch2;
        __sincosf(0.5f * qw[(l * 4 + w) * 2 + 0], &sh, &ch);    // RY
        __sincosf(0.5f * qw[(l * 4 + w) * 2 + 1], &sh2, &ch2);  // RZ
        const int ua = u & ~mask, ub = u | mask;
        const float ar = lds[SRE + col * 17 + ua], ai = lds[SIM + col * 17 + ua];
        const float br = lds[SRE + col * 17 + ub], bi = lds[SIM + col * 17 + ub];
        __syncthreads();
        float nr, ni;
        if (u & mask) { nr = sh * ar + ch * br; ni = sh * ai + ch * bi; }
        else          { nr = ch * ar - sh * br; ni = ch * ai - sh * bi; }
        float rr, ri;
        if (u & mask) { rr = ch2 * nr - sh2 * ni; ri = ch2 * ni + sh2 * nr; }
        else          { rr = ch2 * nr + sh2 * ni; ri = ch2 * ni - sh2 * nr; }
        lds[SRE + col * 17 + u] = rr; lds[SIM + col * 17 + u] = ri;
        __syncthreads();
      }
      // CNOT ring (0,1)(1,2)(2,3)(3,0) as one permutation
      int src = u;
      if (src & 1) src ^= 8;
      if (src & 2) src ^= 1;
      if (src & 4) src ^= 2;
      if (src & 8) src ^= 4;
      const float pr = lds[SRE + col * 17 + src], pi = lds[SIM + col * 17 + src];
      __syncthreads();
      lds[SRE + col * 17 + u] = pr; lds[SIM + col * 17 + u] = pi;
      __syncthreads();
    }

    // M[w][s][t] = sum_u z_w(u) * Re(conj(U[u,s]) U[u,t])
#pragma unroll
    for (int k = 0; k < 4; ++k) {
      const int idx = tid + 256 * k;
      const int w = idx >> 8, s = (idx >> 4) & 15, t = idx & 15;
      const int mask = 8 >> w;
      float acc = 0.0f;
#pragma unroll
      for (int uu = 0; uu < 16; ++uu) {
        const float z = (uu & mask) ? -1.0f : 1.0f;
        acc += z * (lds[SRE + s * 17 + uu] * lds[SRE + t * 17 + uu] +
                    lds[SIM + s * 17 + uu] * lds[SIM + t * 17 + uu]);
      }
      lds[MOF + ((w * 16 + s) * 16 + t)] = acc;
    }
    __syncthreads();

    // A[pq][w]: 16-term sparse Pauli contraction (strided loop: 324 > 256!)
    for (int idx = tid; idx < 324; idx += 256) {
      const int w = idx & 3, pq = idx >> 2;
      const int p = pq / 9, q = pq % 9;
      const int i0 = p / 3, i1 = p % 3, i2 = q / 3, i3 = q % 3;
      float acc = 0.0f;
#pragma unroll
      for (int comb = 0; comb < 16; ++comb) {
        int s = 0, t = 0;
        float coef = 0.0625f;
        int j;
        j = (comb >> 3) & 1; s |= j << 3; t |= ((i0 == 2) ? (j ^ 1) : j) << 3; if (i0 == 1 && j) coef = -coef;
        j = (comb >> 2) & 1; s |= j << 2; t |= ((i1 == 2) ? (j ^ 1) : j) << 2; if (i1 == 1 && j) coef = -coef;
        j = (comb >> 1) & 1; s |= j << 1; t |= ((i2 == 2) ? (j ^ 1) : j) << 1; if (i2 == 1 && j) coef = -coef;
        j = comb & 1;        s |= j;      t |= ((i3 == 2) ? (j ^ 1) : j);      if (i3 == 1 && j) coef = -coef;
        acc = fmaf(coef, lds[MOF + ((w * 16 + s) * 16 + t)], acc);
      }
      lds[AOF + idx] = acc;
    }
    __syncthreads();   // A ready; xt region free
  }

  // ---- 8 staged chunk-rounds (2 phases x 4 chunks), rbA/rbB ping-pong ----
  float aA0 = 0.f, aA1 = 0.f, aA2 = 0.f, aA3 = 0.f;
  float aB0 = 0.f, aB1 = 0.f, aB2 = 0.f, aB3 = 0.f;

  STAGE(rbA); LOADX(rbB, 0, 1); __syncthreads();
  GEMV(aA0, aA1, aA2, aA3, 0);  __syncthreads();
  STAGE(rbB); LOADX(rbA, 0, 2); __syncthreads();
  GEMV(aA0, aA1, aA2, aA3, 1);  __syncthreads();
  STAGE(rbA); LOADX(rbB, 0, 3); __syncthreads();
  GEMV(aA0, aA1, aA2, aA3, 2);  __syncthreads();
  STAGE(rbB); LOADX(rbA, 1, 0); __syncthreads();
  GEMV(aA0, aA1, aA2, aA3, 3);  __syncthreads();
  STAGE(rbA); LOADX(rbB, 1, 1); __syncthreads();
  GEMV(aB0, aB1, aB2, aB3, 0);  __syncthreads();
  STAGE(rbB); LOADX(rbA, 1, 2); __syncthreads();
  GEMV(aB0, aB1, aB2, aB3, 1);  __syncthreads();
  STAGE(rbA); LOADX(rbB, 1, 3); __syncthreads();
  GEMV(aB0, aB1, aB2, aB3, 2);  __syncthreads();
  STAGE(rbB);                   __syncthreads();
  GEMV(aB0, aB1, aB2, aB3, 3);

  // ---- tail: tanh, sincos, g/h for both rows (after final barrier) ----
  float g0[9], h0[9], g1[9], h1[9];
  {
    const float t0 = 1.0f - 2.0f / (__expf(2.0f * (aA0 + bp[0])) + 1.0f);
    const float t1 = 1.0f - 2.0f / (__expf(2.0f * (aA1 + bp[1])) + 1.0f);
    const float t2 = 1.0f - 2.0f / (__expf(2.0f * (aA2 + bp[2])) + 1.0f);
    const float t3 = 1.0f - 2.0f / (__expf(2.0f * (aA3 + bp[3])) + 1.0f);
    float c0, s0, c1, s1, c2, s2, c3, s3;
    __sincosf(t0, &s0, &c0); __sincosf(t1, &s1, &c1);
    __sincosf(t2, &s2, &c2); __sincosf(t3, &s3, &c3);
    g0[0] = 1.f; g0[1] = c1; g0[2] = s1; g0[3] = c0; g0[4] = c0 * c1;
    g0[5] = c0 * s1; g0[6] = s0; g0[7] = s0 * c1; g0[8] = s0 * s1;
    h0[0] = 1.f; h0[1] = c3; h0[2] = s3; h0[3] = c2; h0[4] = c2 * c3;
    h0[5] = c2 * s3; h0[6] = s2; h0[7] = s2 * c3; h0[8] = s2 * s3;
  }
  {
    const float t0 = 1.0f - 2.0f / (__expf(2.0f * (aB0 + bp[0])) + 1.0f);
    const float t1 = 1.0f - 2.0f / (__expf(2.0f * (aB1 + bp[1])) + 1.0f);
    const float t2 = 1.0f - 2.0f / (__expf(2.0f * (aB2 + bp[2])) + 1.0f);
    const float t3 = 1.0f - 2.0f / (__expf(2.0f * (aB3 + bp[3])) + 1.0f);
    float c0, s0, c1, s1, c2, s2, c3, s3;
    __sincosf(t0, &s0, &c0); __sincosf(t1, &s1, &c1);
    __sincosf(t2, &s2, &c2); __sincosf(t3, &s3, &c3);
    g1[0] = 1.f; g1[1] = c1; g1[2] = s1; g1[3] = c0; g1[4] = c0 * c1;
    g1[5] = c0 * s1; g1[6] = s0; g1[7] = s0 * c1; g1[8] = s0 * s1;
    h1[0] = 1.f; h1[1] = c3; h1[2] = s3; h1[3] = c2; h1[4] = c2 * c3;
    h1[5] = c2 * s3; h1[6] = s2; h1[7] = s2 * c3; h1[8] = s2 * s3;
  }

  // ---- contraction: 81 uniform b128 LDS broadcasts shared by both rows ----
  float e00 = 0.f, e01 = 0.f, e02 = 0.f, e03 = 0.f;
  float e10 = 0.f, e11 = 0.f, e12 = 0.f, e13 = 0.f;
#pragma unroll
  for (int p = 0; p < 9; ++p) {
#pragma unroll
    for (int q = 0; q < 9; ++q) {
      const float4 a4 =
          *reinterpret_cast<const float4*>(&lds[AOF + (p * 9 + q) * 4]);
      const float tA = g0[p] * h0[q];
      const float tB = g1[p] * h1[q];
      e00 = fmaf(a4.x, tA, e00); e01 = fmaf(a4.y, tA, e01);
      e02 = fmaf(a4.z, tA, e02); e03 = fmaf(a4.w, tA, e03);
      e10 = fmaf(a4.x, tB, e10); e11 = fmaf(a4.y, tB, e11);
      e12 = fmaf(a4.z, tB, e12); e13 = fmaf(a4.w, tB, e13);
    }
  }
  float4* out4 = reinterpret_cast<float4*>(out);
  out4[row0 + tid]       = make_float4(e00, e01, e02, e03);
  out4[row0 + 256 + tid] = make_float4(e10, e11, e12, e13);
}

extern "C" void kernel_launch(void* const* d_in, const int* in_sizes, int n_in,
                              void* d_out, int out_size, void* d_ws, size_t ws_size,
                              hipStream_t stream) {
  const float* x  = (const float*)d_in[0];
  const float* Wp = (const float*)d_in[1];
  const float* bp = (const float*)d_in[2];
  const float* qw = (const float*)d_in[3];
  float* out = (float*)d_out;
  (void)d_ws; (void)ws_size; (void)n_in; (void)out_size;

  const int B = in_sizes[0] / 64;   // 524288
  qfused_kernel<<<B / 512, 256, 0, stream>>>(x, Wp, bp, qw, out);
}

// Round 8
// 41.999 us; speedup vs baseline: 2.1428x; 2.1428x over previous
//
#include <hip/hip_runtime.h>
#include <cmath>

// Single fused kernel: coalesced LDS staging + b128 LDS GEMV, R=2 rows/thread.
//
// Math: angles = tanh(x@W^T + b); fixed 3-layer circuit = constant 16x16
// unitary U; output collapses to an 81x4 tensor A contracted with g[9]xh[9]
// built from sincos(angles). A recomputed per block in LDS.
//
// KEY FIX vs round 7: amdgpu_waves_per_eu(4,4) pins the register budget to
// 128 VGPR (4 waves/EU). With only __launch_bounds__(256,4) the allocator
// targeted 8 waves/EU (64 VGPR) and spilled ~134 MB of scratch per pass
// (WRITE_SIZE 139 MB, VGPR=64 in round-7 counters). 16 waves/CU is plenty
// for HBM streaming. Ping-pong buffers are named scalars, not arrays.

#define LOADX(R0, R1, R2, R3, P, C)                       \
  R0 = xb[((P) * 256 + 0 * 64) * 16 + (C) * 4];           \
  R1 = xb[((P) * 256 + 1 * 64) * 16 + (C) * 4];           \
  R2 = xb[((P) * 256 + 2 * 64) * 16 + (C) * 4];           \
  R3 = xb[((P) * 256 + 3 * 64) * 16 + (C) * 4];

#define STAGE(R0, R1, R2, R3)                                            \
  *reinterpret_cast<float4*>(&lds[(0 * 64 + rrow) * XS + q4w]) = R0;     \
  *reinterpret_cast<float4*>(&lds[(1 * 64 + rrow) * XS + q4w]) = R1;     \
  *reinterpret_cast<float4*>(&lds[(2 * 64 + rrow) * XS + q4w]) = R2;     \
  *reinterpret_cast<float4*>(&lds[(3 * 64 + rrow) * XS + q4w]) = R3;

#define GEMV(A0, A1, A2, A3, C) {                                          \
  const float4 xv0 = *reinterpret_cast<const float4*>(&lds[tid * XS + 0]); \
  const float4 xv1 = *reinterpret_cast<const float4*>(&lds[tid * XS + 4]); \
  const float4 xv2 = *reinterpret_cast<const float4*>(&lds[tid * XS + 8]); \
  const float4 xv3 = *reinterpret_cast<const float4*>(&lds[tid * XS + 12]);\
  A0 = fmaf(xv0.x, Wp[0 * 64 + (C) * 16 + 0], A0);                         \
  A0 = fmaf(xv0.y, Wp[0 * 64 + (C) * 16 + 1], A0);                         \
  A0 = fmaf(xv0.z, Wp[0 * 64 + (C) * 16 + 2], A0);                         \
  A0 = fmaf(xv0.w, Wp[0 * 64 + (C) * 16 + 3], A0);                         \
  A0 = fmaf(xv1.x, Wp[0 * 64 + (C) * 16 + 4], A0);                         \
  A0 = fmaf(xv1.y, Wp[0 * 64 + (C) * 16 + 5], A0);                         \
  A0 = fmaf(xv1.z, Wp[0 * 64 + (C) * 16 + 6], A0);                         \
  A0 = fmaf(xv1.w, Wp[0 * 64 + (C) * 16 + 7], A0);                         \
  A0 = fmaf(xv2.x, Wp[0 * 64 + (C) * 16 + 8], A0);                         \
  A0 = fmaf(xv2.y, Wp[0 * 64 + (C) * 16 + 9], A0);                         \
  A0 = fmaf(xv2.z, Wp[0 * 64 + (C) * 16 + 10], A0);                        \
  A0 = fmaf(xv2.w, Wp[0 * 64 + (C) * 16 + 11], A0);                        \
  A0 = fmaf(xv3.x, Wp[0 * 64 + (C) * 16 + 12], A0);                        \
  A0 = fmaf(xv3.y, Wp[0 * 64 + (C) * 16 + 13], A0);                        \
  A0 = fmaf(xv3.z, Wp[0 * 64 + (C) * 16 + 14], A0);                        \
  A0 = fmaf(xv3.w, Wp[0 * 64 + (C) * 16 + 15], A0);                        \
  A1 = fmaf(xv0.x, Wp[1 * 64 + (C) * 16 + 0], A1);                         \
  A1 = fmaf(xv0.y, Wp[1 * 64 + (C) * 16 + 1], A1);                         \
  A1 = fmaf(xv0.z, Wp[1 * 64 + (C) * 16 + 2], A1);                         \
  A1 = fmaf(xv0.w, Wp[1 * 64 + (C) * 16 + 3], A1);                         \
  A1 = fmaf(xv1.x, Wp[1 * 64 + (C) * 16 + 4], A1);                         \
  A1 = fmaf(xv1.y, Wp[1 * 64 + (C) * 16 + 5], A1);                         \
  A1 = fmaf(xv1.z, Wp[1 * 64 + (C) * 16 + 6], A1);                         \
  A1 = fmaf(xv1.w, Wp[1 * 64 + (C) * 16 + 7], A1);                         \
  A1 = fmaf(xv2.x, Wp[1 * 64 + (C) * 16 + 8], A1);                         \
  A1 = fmaf(xv2.y, Wp[1 * 64 + (C) * 16 + 9], A1);                         \
  A1 = fmaf(xv2.z, Wp[1 * 64 + (C) * 16 + 10], A1);                        \
  A1 = fmaf(xv2.w, Wp[1 * 64 + (C) * 16 + 11], A1);                        \
  A1 = fmaf(xv3.x, Wp[1 * 64 + (C) * 16 + 12], A1);                        \
  A1 = fmaf(xv3.y, Wp[1 * 64 + (C) * 16 + 13], A1);                        \
  A1 = fmaf(xv3.z, Wp[1 * 64 + (C) * 16 + 14], A1);                        \
  A1 = fmaf(xv3.w, Wp[1 * 64 + (C) * 16 + 15], A1);                        \
  A2 = fmaf(xv0.x, Wp[2 * 64 + (C) * 16 + 0], A2);                         \
  A2 = fmaf(xv0.y, Wp[2 * 64 + (C) * 16 + 1], A2);                         \
  A2 = fmaf(xv0.z, Wp[2 * 64 + (C) * 16 + 2], A2);                         \
  A2 = fmaf(xv0.w, Wp[2 * 64 + (C) * 16 + 3], A2);                         \
  A2 = fmaf(xv1.x, Wp[2 * 64 + (C) * 16 + 4], A2);                         \
  A2 = fmaf(xv1.y, Wp[2 * 64 + (C) * 16 + 5], A2);                         \
  A2 = fmaf(xv1.z, Wp[2 * 64 + (C) * 16 + 6], A2);                         \
  A2 = fmaf(xv1.w, Wp[2 * 64 + (C) * 16 + 7], A2);                         \
  A2 = fmaf(xv2.x, Wp[2 * 64 + (C) * 16 + 8], A2);                         \
  A2 = fmaf(xv2.y, Wp[2 * 64 + (C) * 16 + 9], A2);                         \
  A2 = fmaf(xv2.z, Wp[2 * 64 + (C) * 16 + 10], A2);                        \
  A2 = fmaf(xv2.w, Wp[2 * 64 + (C) * 16 + 11], A2);                        \
  A2 = fmaf(xv3.x, Wp[2 * 64 + (C) * 16 + 12], A2);                        \
  A2 = fmaf(xv3.y, Wp[2 * 64 + (C) * 16 + 13], A2);                        \
  A2 = fmaf(xv3.z, Wp[2 * 64 + (C) * 16 + 14], A2);                        \
  A2 = fmaf(xv3.w, Wp[2 * 64 + (C) * 16 + 15], A2);                        \
  A3 = fmaf(xv0.x, Wp[3 * 64 + (C) * 16 + 0], A3);                         \
  A3 = fmaf(xv0.y, Wp[3 * 64 + (C) * 16 + 1], A3);                         \
  A3 = fmaf(xv0.z, Wp[3 * 64 + (C) * 16 + 2], A3);                         \
  A3 = fmaf(xv0.w, Wp[3 * 64 + (C) * 16 + 3], A3);                         \
  A3 = fmaf(xv1.x, Wp[3 * 64 + (C) * 16 + 4], A3);                         \
  A3 = fmaf(xv1.y, Wp[3 * 64 + (C) * 16 + 5], A3);                         \
  A3 = fmaf(xv1.z, Wp[3 * 64 + (C) * 16 + 6], A3);                         \
  A3 = fmaf(xv1.w, Wp[3 * 64 + (C) * 16 + 7], A3);                         \
  A3 = fmaf(xv2.x, Wp[3 * 64 + (C) * 16 + 8], A3);                         \
  A3 = fmaf(xv2.y, Wp[3 * 64 + (C) * 16 + 9], A3);                         \
  A3 = fmaf(xv2.z, Wp[3 * 64 + (C) * 16 + 10], A3);                        \
  A3 = fmaf(xv2.w, Wp[3 * 64 + (C) * 16 + 11], A3);                        \
  A3 = fmaf(xv3.x, Wp[3 * 64 + (C) * 16 + 12], A3);                        \
  A3 = fmaf(xv3.y, Wp[3 * 64 + (C) * 16 + 13], A3);                        \
  A3 = fmaf(xv3.z, Wp[3 * 64 + (C) * 16 + 14], A3);                        \
  A3 = fmaf(xv3.w, Wp[3 * 64 + (C) * 16 + 15], A3); }

__global__ __launch_bounds__(256)
__attribute__((amdgpu_waves_per_eu(4, 4)))    // pin 4 waves/EU -> 128 VGPR budget, NO spill
void qfused_kernel(
    const float* __restrict__ x,    // [B][64]
    const float* __restrict__ Wp,   // [4][64]
    const float* __restrict__ bp,   // [4]
    const float* __restrict__ qw,   // [3][4][2]
    float* __restrict__ out)        // [B][4]
{
  constexpr int XS  = 20;           // xt word stride: 80B rows, 16B-aligned
  constexpr int AOF = 256 * XS;     // 5120
  __shared__ alignas(16) float lds[256 * XS + 324];   // 21.3 KB
  constexpr int SRE = 0;            // prep scratch inside xt region (dead later)
  constexpr int SIM = 272;
  constexpr int MOF = 544;

  const int tid = threadIdx.x;
  const size_t row0 = (size_t)blockIdx.x * 512;
  const int rrow = tid >> 2;            // staging row within 64-row group
  const int q4w  = (tid & 3) << 2;      // word offset within 16-feat chunk
  const float4* xb = reinterpret_cast<const float4*>(x) +
                     (row0 + (size_t)rrow) * 16 + (tid & 3);

  // ---- prefetch (phase0, chunk0); in flight during prep ----
  float4 rbA0, rbA1, rbA2, rbA3, rbB0, rbB1, rbB2, rbB3;
  LOADX(rbA0, rbA1, rbA2, rbA3, 0, 0);

  // ---- prep: build A[81][4] at lds[AOF] (256 thr = 16 cols x 16 amps) ----
  {
    const int col = tid >> 4;
    const int u   = tid & 15;
    lds[SRE + col * 17 + u] = (u == col) ? 1.0f : 0.0f;
    lds[SIM + col * 17 + u] = 0.0f;
    __syncthreads();

#pragma unroll
    for (int l = 0; l < 3; ++l) {
#pragma unroll
      for (int w = 0; w < 4; ++w) {
        const int mask = 8 >> w;     // wire 0 = MSB
        float sh, ch, sh2, ch2;
        __sincosf(0.5f * qw[(l * 4 + w) * 2 + 0], &sh, &ch);    // RY
        __sincosf(0.5f * qw[(l * 4 + w) * 2 + 1], &sh2, &ch2);  // RZ
        const int ua = u & ~mask, ub = u | mask;
        const float ar = lds[SRE + col * 17 + ua], ai = lds[SIM + col * 17 + ua];
        const float br = lds[SRE + col * 17 + ub], bi = lds[SIM + col * 17 + ub];
        __syncthreads();
        float nr, ni;
        if (u & mask) { nr = sh * ar + ch * br; ni = sh * ai + ch * bi; }
        else          { nr = ch * ar - sh * br; ni = ch * ai - sh * bi; }
        float rr, ri;
        if (u & mask) { rr = ch2 * nr - sh2 * ni; ri = ch2 * ni + sh2 * nr; }
        else          { rr = ch2 * nr + sh2 * ni; ri = ch2 * ni - sh2 * nr; }
        lds[SRE + col * 17 + u] = rr; lds[SIM + col * 17 + u] = ri;
        __syncthreads();
      }
      // CNOT ring (0,1)(1,2)(2,3)(3,0) as one permutation
      int src = u;
      if (src & 1) src ^= 8;
      if (src & 2) src ^= 1;
      if (src & 4) src ^= 2;
      if (src & 8) src ^= 4;
      const float pr = lds[SRE + col * 17 + src], pi = lds[SIM + col * 17 + src];
      __syncthreads();
      lds[SRE + col * 17 + u] = pr; lds[SIM + col * 17 + u] = pi;
      __syncthreads();
    }

    // M[w][s][t] = sum_u z_w(u) * Re(conj(U[u,s]) U[u,t])
#pragma unroll
    for (int k = 0; k < 4; ++k) {
      const int idx = tid + 256 * k;
      const int w = idx >> 8, s = (idx >> 4) & 15, t = idx & 15;
      const int mask = 8 >> w;
      float acc = 0.0f;
#pragma unroll
      for (int uu = 0; uu < 16; ++uu) {
        const float z = (uu & mask) ? -1.0f : 1.0f;
        acc += z * (lds[SRE + s * 17 + uu] * lds[SRE + t * 17 + uu] +
                    lds[SIM + s * 17 + uu] * lds[SIM + t * 17 + uu]);
      }
      lds[MOF + ((w * 16 + s) * 16 + t)] = acc;
    }
    __syncthreads();

    // A[pq][w]: 16-term sparse Pauli contraction (strided loop: 324 > 256!)
    for (int idx = tid; idx < 324; idx += 256) {
      const int w = idx & 3, pq = idx >> 2;
      const int p = pq / 9, q = pq % 9;
      const int i0 = p / 3, i1 = p % 3, i2 = q / 3, i3 = q % 3;
      float acc = 0.0f;
#pragma unroll
      for (int comb = 0; comb < 16; ++comb) {
        int s = 0, t = 0;
        float coef = 0.0625f;
        int j;
        j = (comb >> 3) & 1; s |= j << 3; t |= ((i0 == 2) ? (j ^ 1) : j) << 3; if (i0 == 1 && j) coef = -coef;
        j = (comb >> 2) & 1; s |= j << 2; t |= ((i1 == 2) ? (j ^ 1) : j) << 2; if (i1 == 1 && j) coef = -coef;
        j = (comb >> 1) & 1; s |= j << 1; t |= ((i2 == 2) ? (j ^ 1) : j) << 1; if (i2 == 1 && j) coef = -coef;
        j = comb & 1;        s |= j;      t |= ((i3 == 2) ? (j ^ 1) : j);      if (i3 == 1 && j) coef = -coef;
        acc = fmaf(coef, lds[MOF + ((w * 16 + s) * 16 + t)], acc);
      }
      lds[AOF + idx] = acc;
    }
    __syncthreads();   // A ready; xt region free
  }

  // ---- 8 staged chunk-rounds (2 phases x 4 chunks), named ping-pong ----
  float aA0 = 0.f, aA1 = 0.f, aA2 = 0.f, aA3 = 0.f;
  float aB0 = 0.f, aB1 = 0.f, aB2 = 0.f, aB3 = 0.f;

  STAGE(rbA0, rbA1, rbA2, rbA3); LOADX(rbB0, rbB1, rbB2, rbB3, 0, 1); __syncthreads();
  GEMV(aA0, aA1, aA2, aA3, 0);   __syncthreads();
  STAGE(rbB0, rbB1, rbB2, rbB3); LOADX(rbA0, rbA1, rbA2, rbA3, 0, 2); __syncthreads();
  GEMV(aA0, aA1, aA2, aA3, 1);   __syncthreads();
  STAGE(rbA0, rbA1, rbA2, rbA3); LOADX(rbB0, rbB1, rbB2, rbB3, 0, 3); __syncthreads();
  GEMV(aA0, aA1, aA2, aA3, 2);   __syncthreads();
  STAGE(rbB0, rbB1, rbB2, rbB3); LOADX(rbA0, rbA1, rbA2, rbA3, 1, 0); __syncthreads();
  GEMV(aA0, aA1, aA2, aA3, 3);   __syncthreads();
  STAGE(rbA0, rbA1, rbA2, rbA3); LOADX(rbB0, rbB1, rbB2, rbB3, 1, 1); __syncthreads();
  GEMV(aB0, aB1, aB2, aB3, 0);   __syncthreads();
  STAGE(rbB0, rbB1, rbB2, rbB3); LOADX(rbA0, rbA1, rbA2, rbA3, 1, 2); __syncthreads();
  GEMV(aB0, aB1, aB2, aB3, 1);   __syncthreads();
  STAGE(rbA0, rbA1, rbA2, rbA3); LOADX(rbB0, rbB1, rbB2, rbB3, 1, 3); __syncthreads();
  GEMV(aB0, aB1, aB2, aB3, 2);   __syncthreads();
  STAGE(rbB0, rbB1, rbB2, rbB3); __syncthreads();
  GEMV(aB0, aB1, aB2, aB3, 3);

  // ---- tail: tanh, sincos, g/h (compile-time-indexed arrays) ----
  float g0[9], h0[9], g1[9], h1[9];
  {
    const float t0 = 1.0f - 2.0f / (__expf(2.0f * (aA0 + bp[0])) + 1.0f);
    const float t1 = 1.0f - 2.0f / (__expf(2.0f * (aA1 + bp[1])) + 1.0f);
    const float t2 = 1.0f - 2.0f / (__expf(2.0f * (aA2 + bp[2])) + 1.0f);
    const float t3 = 1.0f - 2.0f / (__expf(2.0f * (aA3 + bp[3])) + 1.0f);
    float c0, s0, c1, s1, c2, s2, c3, s3;
    __sincosf(t0, &s0, &c0); __sincosf(t1, &s1, &c1);
    __sincosf(t2, &s2, &c2); __sincosf(t3, &s3, &c3);
    g0[0] = 1.f; g0[1] = c1; g0[2] = s1; g0[3] = c0; g0[4] = c0 * c1;
    g0[5] = c0 * s1; g0[6] = s0; g0[7] = s0 * c1; g0[8] = s0 * s1;
    h0[0] = 1.f; h0[1] = c3; h0[2] = s3; h0[3] = c2; h0[4] = c2 * c3;
    h0[5] = c2 * s3; h0[6] = s2; h0[7] = s2 * c3; h0[8] = s2 * s3;
  }
  {
    const float t0 = 1.0f - 2.0f / (__expf(2.0f * (aB0 + bp[0])) + 1.0f);
    const float t1 = 1.0f - 2.0f / (__expf(2.0f * (aB1 + bp[1])) + 1.0f);
    const float t2 = 1.0f - 2.0f / (__expf(2.0f * (aB2 + bp[2])) + 1.0f);
    const float t3 = 1.0f - 2.0f / (__expf(2.0f * (aB3 + bp[3])) + 1.0f);
    float c0, s0, c1, s1, c2, s2, c3, s3;
    __sincosf(t0, &s0, &c0); __sincosf(t1, &s1, &c1);
    __sincosf(t2, &s2, &c2); __sincosf(t3, &s3, &c3);
    g1[0] = 1.f; g1[1] = c1; g1[2] = s1; g1[3] = c0; g1[4] = c0 * c1;
    g1[5] = c0 * s1; g1[6] = s0; g1[7] = s0 * c1; g1[8] = s0 * s1;
    h1[0] = 1.f; h1[1] = c3; h1[2] = s3; h1[3] = c2; h1[4] = c2 * c3;
    h1[5] = c2 * s3; h1[6] = s2; h1[7] = s2 * c3; h1[8] = s2 * s3;
  }

  // ---- contraction: 81 uniform b128 LDS broadcasts shared by both rows ----
  float e00 = 0.f, e01 = 0.f, e02 = 0.f, e03 = 0.f;
  float e10 = 0.f, e11 = 0.f, e12 = 0.f, e13 = 0.f;
#pragma unroll
  for (int p = 0; p < 9; ++p) {
#pragma unroll
    for (int q = 0; q < 9; ++q) {
      const float4 a4 =
          *reinterpret_cast<const float4*>(&lds[AOF + (p * 9 + q) * 4]);
      const float tA = g0[p] * h0[q];
      const float tB = g1[p] * h1[q];
      e00 = fmaf(a4.x, tA, e00); e01 = fmaf(a4.y, tA, e01);
      e02 = fmaf(a4.z, tA, e02); e03 = fmaf(a4.w, tA, e03);
      e10 = fmaf(a4.x, tB, e10); e11 = fmaf(a4.y, tB, e11);
      e12 = fmaf(a4.z, tB, e12); e13 = fmaf(a4.w, tB, e13);
    }
  }
  float4* out4 = reinterpret_cast<float4*>(out);
  out4[row0 + tid]       = make_float4(e00, e01, e02, e03);
  out4[row0 + 256 + tid] = make_float4(e10, e11, e12, e13);
}

extern "C" void kernel_launch(void* const* d_in, const int* in_sizes, int n_in,
                              void* d_out, int out_size, void* d_ws, size_t ws_size,
                              hipStream_t stream) {
  const float* x  = (const float*)d_in[0];
  const float* Wp = (const float*)d_in[1];
  const float* bp = (const float*)d_in[2];
  const float* qw = (const float*)d_in[3];
  float* out = (float*)d_out;
  (void)d_ws; (void)ws_size; (void)n_in; (void)out_size;

  const int B = in_sizes[0] / 64;   // 524288
  qfused_kernel<<<B / 512, 256, 0, stream>>>(x, Wp, bp, qw, out);
}